// Round 6
// baseline (606.400 us; speedup 1.0000x reference)
//
#include <hip/hip_runtime.h>
#include <cfloat>
#include <stdint.h>

// Problem constants
#define NROWS   32768
#define NCODES  8192
#define KDIM    256
#define QOUT_OFFSET (NROWS * KDIM)

// Main-kernel tiling
#define BM      64             // rows per block
#define BN      128            // codes per code-tile
#define BK      32             // k per chunk
#define NCT     (NCODES / BN)  // 64
#define NKC     (KDIM / BK)    // 8
#define NIT     (NCT * NKC)    // 512 iterations
#define THREADS 256            // 4 waves

// Panel geometry (bf16, 32 k per row + 16B pad)
#define ROWB 80
#define APAN (BM * ROWB)       // 5120 B per split
#define BPAN (BN * ROWB)       // 10240 B per split
#define ABUF (2 * APAN)        // hi+lo 10240 B
#define BBUF (2 * BPAN)        // hi+lo 20480 B
// total LDS: 2*(ABUF+BBUF) = 61440... plus nothing else = fits 2 blocks/CU

typedef __bf16 bf16x4 __attribute__((ext_vector_type(4)));
typedef __bf16 bf16x8 __attribute__((ext_vector_type(8)));
typedef float  f32x4  __attribute__((ext_vector_type(4)));

// ---------------------------------------------------------------------------
// K1: build codebook hi/lo bf16 panels + cnorm in one pass.
// Panel (pt = code/128, kc): [128 codes x 80 B] hi, [128 x 80 B] lo.
// Block = 256 thr handles 64 codes; thread: row=t>>2, seg=t&3 (16 float4).
// ---------------------------------------------------------------------------
__global__ void vq_panel_kernel(const float* __restrict__ cb,
                                char* __restrict__ cbP,
                                float* __restrict__ cnorm) {
    const int t    = threadIdx.x;
    const int row  = t >> 2;
    const int seg  = t & 3;
    const int code = blockIdx.x * 64 + row;
    const int pt   = code >> 7;          // /128
    const int cl   = code & 127;
    const float4* cb4 = (const float4*)cb;

    float ssq = 0.f;
    #pragma unroll
    for (int i = 0; i < 16; ++i) {
        int f = seg * 16 + i;            // float4 index in row, 0..63
        float4 v = cb4[(size_t)code * 64 + f];
        int k  = f * 4;
        int kc = k >> 5;
        int kl = k & 31;
        bf16x4 h, l;
        float xs[4] = {v.x, v.y, v.z, v.w};
        #pragma unroll
        for (int e = 0; e < 4; ++e) {
            __bf16 hh = (__bf16)xs[e];
            h[e] = hh;
            l[e] = (__bf16)(xs[e] - (float)hh);
            ssq  = fmaf(xs[e], xs[e], ssq);
        }
        char* base = cbP + ((size_t)(pt * NKC + kc)) * BBUF
                         + (size_t)cl * ROWB + (size_t)kl * 2;
        *(bf16x4*)base          = h;
        *(bf16x4*)(base + BPAN) = l;
    }
    // quad reduction (seg = t&3 consecutive lanes)
    ssq += __shfl_xor(ssq, 1, 64);
    ssq += __shfl_xor(ssq, 2, 64);
    if (seg == 0) cnorm[code] = ssq;
}

// ---------------------------------------------------------------------------
// async 16B global->LDS copy (wave-uniform LDS base + lane*16)
// ---------------------------------------------------------------------------
__device__ __forceinline__ void async_copy16(const void* g, void* l) {
    __builtin_amdgcn_global_load_lds(
        (const __attribute__((address_space(1))) uint32_t*)g,
        (__attribute__((address_space(3))) uint32_t*)l, 16, 0, 0);
}

// ---------------------------------------------------------------------------
// K2: distances via split-bf16 MFMA + argmin. Writes idx floats only.
// 4 waves; wave w owns codes w*32..w*32+31 of the 128-code tile, all 64 rows.
// Wave tile 64x32 = 4x2 MFMA 16x16 tiles; 3 split passes (hh, h*lo, lo*h).
// LDS exactly 2*(ABUF+BBUF)=61440 B -> 2 blocks/CU; barriers decoupled.
// ---------------------------------------------------------------------------
__global__ __launch_bounds__(THREADS, 2) void vq_main_kernel(
        const float* __restrict__ z, const char* __restrict__ cbP,
        const float* __restrict__ cnorm, float* __restrict__ idx_out) {

    __shared__ __align__(16) char ldsbuf[2 * ABUF + 2 * BBUF];  // 61440 B

    const int t    = threadIdx.x;
    const int wave = t >> 6;
    const int lane = t & 63;
    const int row0 = blockIdx.x * BM;
    const int l15  = lane & 15;
    const int q16  = (lane >> 4) * 16;     // byte offset of k-octet in row

    const float4* z4 = (const float4*)z;

    // A staging: thread t -> row t>>2 (0..63), k-segment t&3 (8 elems)
    const int arow = t >> 2;
    const int aseg = t & 3;

    f32x4 acc[4][2];
    float mv[16];
    int   mi[16];
    #pragma unroll
    for (int i = 0; i < 4; ++i)
        #pragma unroll
        for (int j = 0; j < 2; ++j)
            acc[i][j] = (f32x4){0.f, 0.f, 0.f, 0.f};
    #pragma unroll
    for (int s = 0; s < 16; ++s) { mv[s] = FLT_MAX; mi[s] = 0; }

    // ---- prologue: stage iteration 0 into buffer 0 ----
    {
        // B async: 20 chunks of 1024 B, 5 per wave
        char* Bdst = ldsbuf + 2 * ABUF;
        #pragma unroll
        for (int c = 0; c < 5; ++c) {
            int off = (wave * 5 + c) * 1024 + lane * 16;
            async_copy16(cbP + off, Bdst + off);
        }
        float4 za = z4[(size_t)(row0 + arow) * 64 + aseg * 2 + 0];
        float4 zb = z4[(size_t)(row0 + arow) * 64 + aseg * 2 + 1];
        float xs[8] = {za.x, za.y, za.z, za.w, zb.x, zb.y, zb.z, zb.w};
        bf16x8 hv, lv;
        #pragma unroll
        for (int e = 0; e < 8; ++e) {
            __bf16 hh = (__bf16)xs[e];
            hv[e] = hh;
            lv[e] = (__bf16)(xs[e] - (float)hh);
        }
        *(bf16x8*)(ldsbuf + arow * ROWB + aseg * 16)        = hv;
        *(bf16x8*)(ldsbuf + APAN + arow * ROWB + aseg * 16) = lv;
    }

    for (int n = 0; n < NIT; ++n) {
        const int ct = n >> 3;
        const int kc = n & 7;
        const int p  = n & 1;

        __syncthreads();   // buffers[p] ready, buffers[p^1] free

        const char* Ab = ldsbuf + p * ABUF;
        const char* Bb = ldsbuf + 2 * ABUF + p * BBUF;

        // ---- issue async B staging for n+1 into buffer p^1 ----
        if (n + 1 < NIT) {
            const char* gsrc = cbP + (size_t)(n + 1) * BBUF;
            char* Bdst = ldsbuf + 2 * ABUF + (p ^ 1) * BBUF;
            #pragma unroll
            for (int c = 0; c < 5; ++c) {
                int off = (wave * 5 + c) * 1024 + lane * 16;
                async_copy16(gsrc + off, Bdst + off);
            }
        }
        // ---- issue z loads for n+1 (consumed after compute) ----
        float4 za, zb;
        if (n + 1 < NIT) {
            int kc1 = (n + 1) & 7;
            za = z4[(size_t)(row0 + arow) * 64 + kc1 * 8 + aseg * 2 + 0];
            zb = z4[(size_t)(row0 + arow) * 64 + kc1 * 8 + aseg * 2 + 1];
        }

        // ---- compute: 3-phase split products, 8 MFMAs each ----
        bf16x8 ah[4], bh[2], bl[2], al[4];
        #pragma unroll
        for (int i = 0; i < 4; ++i)
            ah[i] = *(const bf16x8*)(Ab + (i * 16 + l15) * ROWB + q16);
        #pragma unroll
        for (int j = 0; j < 2; ++j)
            bh[j] = *(const bf16x8*)(Bb + (wave * 32 + j * 16 + l15) * ROWB + q16);
        #pragma unroll
        for (int i = 0; i < 4; ++i)
            #pragma unroll
            for (int j = 0; j < 2; ++j)
                acc[i][j] = __builtin_amdgcn_mfma_f32_16x16x32_bf16(
                                ah[i], bh[j], acc[i][j], 0, 0, 0);
        #pragma unroll
        for (int j = 0; j < 2; ++j)
            bl[j] = *(const bf16x8*)(Bb + BPAN + (wave * 32 + j * 16 + l15) * ROWB + q16);
        #pragma unroll
        for (int i = 0; i < 4; ++i)
            #pragma unroll
            for (int j = 0; j < 2; ++j)
                acc[i][j] = __builtin_amdgcn_mfma_f32_16x16x32_bf16(
                                ah[i], bl[j], acc[i][j], 0, 0, 0);
        #pragma unroll
        for (int i = 0; i < 4; ++i)
            al[i] = *(const bf16x8*)(Ab + APAN + (i * 16 + l15) * ROWB + q16);
        #pragma unroll
        for (int i = 0; i < 4; ++i)
            #pragma unroll
            for (int j = 0; j < 2; ++j)
                acc[i][j] = __builtin_amdgcn_mfma_f32_16x16x32_bf16(
                                al[i], bh[j], acc[i][j], 0, 0, 0);

        // ---- epilogue at end of code-tile: dist = ||c||^2 - 2 z.c ----
        if (kc == 7) {
            #pragma unroll
            for (int j = 0; j < 2; ++j) {
                int code = ct * BN + wave * 32 + j * 16 + l15;
                float cn = cnorm[code];          // L2-resident, every 8th iter
                #pragma unroll
                for (int i = 0; i < 4; ++i) {
                    #pragma unroll
                    for (int r = 0; r < 4; ++r) {
                        float d = fmaf(-2.f, acc[i][j][r], cn);
                        int s = i * 4 + r;
                        if (d < mv[s]) { mv[s] = d; mi[s] = code; }
                    }
                    acc[i][j] = (f32x4){0.f, 0.f, 0.f, 0.f};
                }
            }
        }

        // ---- convert + LDS-write A for n+1 into buffer p^1 ----
        if (n + 1 < NIT) {
            float xs[8] = {za.x, za.y, za.z, za.w, zb.x, zb.y, zb.z, zb.w};
            bf16x8 hv, lv;
            #pragma unroll
            for (int e = 0; e < 8; ++e) {
                __bf16 hh = (__bf16)xs[e];
                hv[e] = hh;
                lv[e] = (__bf16)(xs[e] - (float)hh);
            }
            char* Adst = ldsbuf + (p ^ 1) * ABUF;
            *(bf16x8*)(Adst + arow * ROWB + aseg * 16)        = hv;
            *(bf16x8*)(Adst + APAN + arow * ROWB + aseg * 16) = lv;
        }
    }

    // ---- reduction: 16-lane butterfly (codes within wave), then cross-wave
    #pragma unroll
    for (int s = 0; s < 16; ++s) {
        #pragma unroll
        for (int m = 1; m <= 8; m <<= 1) {
            float ov = __shfl_xor(mv[s], m, 64);
            int   oi = __shfl_xor(mi[s], m, 64);
            if (ov < mv[s] || (ov == mv[s] && oi < mi[s])) { mv[s] = ov; mi[s] = oi; }
        }
    }
    __syncthreads();   // safe to reuse ldsbuf
    float* redV = (float*)ldsbuf;               // [4 wave][64 rows]
    int*   redI = (int*)(ldsbuf + 4 * BM * 4);  // [4 wave][64 rows]
    if (l15 == 0) {
        int q = lane >> 4;
        #pragma unroll
        for (int i = 0; i < 4; ++i)
            #pragma unroll
            for (int r = 0; r < 4; ++r) {
                int ml = i * 16 + q * 4 + r;     // row in 0..63
                redV[wave * BM + ml] = mv[i * 4 + r];
                redI[wave * BM + ml] = mi[i * 4 + r];
            }
    }
    __syncthreads();
    if (t < BM) {
        float bv = redV[t];
        int   bi = redI[t];
        #pragma unroll
        for (int w = 1; w < 4; ++w) {
            float v  = redV[w * BM + t];
            int   id = redI[w * BM + t];
            if (v < bv || (v == bv && id < bi)) { bv = v; bi = id; }
        }
        idx_out[row0 + t] = (float)bi;
    }
}

// ---------------------------------------------------------------------------
// K3: gather codebook rows into quantized output (bit-exact fp32).
// Separate dispatch => global barrier; overwrites the cbP scratch region.
// ---------------------------------------------------------------------------
__global__ void vq_gather_kernel(const float* __restrict__ cb,
                                 const float* __restrict__ idx_f,
                                 float* __restrict__ quant) {
    const int t   = threadIdx.x;
    const int row = blockIdx.x * 64 + (t >> 2);
    const int seg = t & 3;
    const int best = (int)idx_f[row];
    const float4* src = (const float4*)cb + (size_t)best * (KDIM / 4);
    float4* dst = (float4*)quant + (size_t)row * (KDIM / 4);
    #pragma unroll
    for (int i = 0; i < 16; ++i)
        dst[seg * 16 + i] = src[seg * 16 + i];
}

// ---------------------------------------------------------------------------
extern "C" void kernel_launch(void* const* d_in, const int* in_sizes, int n_in,
                              void* d_out, int out_size, void* d_ws, size_t ws_size,
                              hipStream_t stream) {
    const float* z  = (const float*)d_in[0];
    const float* cb = (const float*)d_in[1];
    float* quant   = (float*)d_out;
    float* idx_out = (float*)d_out + QOUT_OFFSET;
    float* cnorm   = (float*)d_ws;           // 32 KB scratch
    char*  cbP     = (char*)d_out;           // 10.5 MB panel scratch inside
                                             // quant region; K3 overwrites it

    vq_panel_kernel<<<NCODES / 64, 256, 0, stream>>>(cb, cbP, cnorm);
    vq_main_kernel<<<NROWS / BM, THREADS, 0, stream>>>(z, cbP, cnorm, idx_out);
    vq_gather_kernel<<<NROWS / 64, 256, 0, stream>>>(cb, idx_out, quant);
}

// Round 7
// 567.672 us; speedup vs baseline: 1.0682x; 1.0682x over previous
//
#include <hip/hip_runtime.h>
#include <cfloat>
#include <stdint.h>

// Problem constants
#define NROWS   32768
#define NCODES  8192
#define KDIM    256
#define QOUT_OFFSET (NROWS * KDIM)

// Main-kernel tiling
#define BM      64             // rows per block
#define BN      128            // codes per code-tile
#define NQ      4              // codebook quarters
#define CODES_Q (NCODES / NQ)  // 2048
#define NKC     (KDIM / 32)    // 8
#define NIT     (CODES_Q / BN * NKC)  // 16 ct * 8 kc = 128
#define THREADS 256            // 4 waves

// Fragment-order panel geometry (NO padding)
#define APAN 4096              // 64 rows * 32 k * 2 B, one split
#define ABUF (2 * APAN)        // hi+lo 8192
#define BPAN 8192              // 128 codes * 32 k * 2 B, one split
#define BBUF (2 * BPAN)        // hi+lo 16384
// LDS: 2*(ABUF+BBUF) = 49152 B -> 3 blocks/CU

typedef __bf16 bf16x4 __attribute__((ext_vector_type(4)));
typedef __bf16 bf16x8 __attribute__((ext_vector_type(8)));
typedef float  f32x4  __attribute__((ext_vector_type(4)));

// ---------------------------------------------------------------------------
// K1: codebook -> hi/lo bf16 panels in MFMA-fragment order, + cnorm.
// Panel p = (code>>7)*8 + kc. Within panel: tile j=(code&127)>>4,
// frag-lane = ((kl>>3)<<4) | (code&15), slot byte = (j*64+lane)*16 + (kl&7)*2.
// ---------------------------------------------------------------------------
__global__ void vq_panel_kernel(const float* __restrict__ cb,
                                char* __restrict__ cbP,
                                float* __restrict__ cnorm) {
    const int t    = threadIdx.x;
    const int row  = t >> 2;
    const int seg  = t & 3;
    const int code = blockIdx.x * 64 + row;
    const int cl   = code & 127;
    const int pt   = code >> 7;
    const float4* cb4 = (const float4*)cb;

    float ssq = 0.f;
    #pragma unroll
    for (int i = 0; i < 16; ++i) {
        int f = seg * 16 + i;            // float4 index in row, 0..63
        float4 v = cb4[(size_t)code * 64 + f];
        int k   = f * 4;
        int kc  = k >> 5;
        int kl  = k & 31;
        int oct = kl >> 3;
        int rem = kl & 7;                // 0 or 4
        bf16x4 h, l;
        float xs[4] = {v.x, v.y, v.z, v.w};
        #pragma unroll
        for (int e = 0; e < 4; ++e) {
            __bf16 hh = (__bf16)xs[e];
            h[e] = hh;
            l[e] = (__bf16)(xs[e] - (float)hh);
            ssq  = fmaf(xs[e], xs[e], ssq);
        }
        int lanefrag = (oct << 4) | (cl & 15);
        char* base = cbP + ((size_t)(pt * NKC + kc)) * BBUF
                         + ((cl >> 4) * 64 + lanefrag) * 16 + rem * 2;
        *(bf16x4*)base          = h;
        *(bf16x4*)(base + BPAN) = l;
    }
    ssq += __shfl_xor(ssq, 1, 64);
    ssq += __shfl_xor(ssq, 2, 64);
    if (seg == 0) cnorm[code] = ssq;
}

// ---------------------------------------------------------------------------
__device__ __forceinline__ void async_copy16(const void* g, void* l) {
    __builtin_amdgcn_global_load_lds(
        (const __attribute__((address_space(1))) uint32_t*)g,
        (__attribute__((address_space(3))) uint32_t*)l, 16, 0, 0);
}

// ---------------------------------------------------------------------------
// K2: split-bf16 MFMA distances + per-quarter argmin partials.
// Grid 2048: q = bid>>9 (codebook quarter), rowblk = bid&511.
// 4 waves; wave w owns code-tiles {2w, 2w+1} (32 codes), all 64 rows.
// 3 split passes (hh, h*lo, lo*h) -> exact fp32-grade distances.
// ---------------------------------------------------------------------------
__global__ __launch_bounds__(THREADS, 3) void vq_main_kernel(
        const float* __restrict__ z, const char* __restrict__ cbP,
        const float* __restrict__ cnorm,
        float* __restrict__ partD, int* __restrict__ partI) {

    __shared__ __align__(16) char ldsbuf[2 * ABUF + 2 * BBUF];  // 49152 B

    const int t     = threadIdx.x;
    const int wave  = t >> 6;
    const int lane  = t & 63;
    const int l15   = lane & 15;
    const int q     = blockIdx.x >> 9;
    const int row0  = (blockIdx.x & 511) * BM;
    const int qcode = q * CODES_Q;
    const size_t panel0 = (size_t)q * NIT;   // 128 panels per quarter

    const float4* z4 = (const float4*)z;

    // A staging: thread t -> row t>>2 (0..63), k-octet-pair seg t&3
    const int arow = t >> 2;
    const int aseg = t & 3;
    const int aoff = (((arow >> 4) * 64) + (aseg << 4) + (arow & 15)) * 16;

    f32x4 acc[4][2];
    float mv[16];
    int   mi[16];
    #pragma unroll
    for (int i = 0; i < 4; ++i)
        #pragma unroll
        for (int j = 0; j < 2; ++j)
            acc[i][j] = (f32x4){0.f, 0.f, 0.f, 0.f};
    #pragma unroll
    for (int s = 0; s < 16; ++s) { mv[s] = FLT_MAX; mi[s] = 0; }

    // ---- prologue: stage iteration 0 into buffer 0 ----
    {
        char* Bdst = ldsbuf + 2 * ABUF;
        const char* gsrc = cbP + panel0 * BBUF;
        #pragma unroll
        for (int c = 0; c < 4; ++c) {
            int off = (wave * 4 + c) * 1024 + lane * 16;
            async_copy16(gsrc + off, Bdst + off);
        }
        float4 za = z4[(size_t)(row0 + arow) * 64 + aseg * 2 + 0];
        float4 zb = z4[(size_t)(row0 + arow) * 64 + aseg * 2 + 1];
        float xs[8] = {za.x, za.y, za.z, za.w, zb.x, zb.y, zb.z, zb.w};
        bf16x8 hv, lv;
        #pragma unroll
        for (int e = 0; e < 8; ++e) {
            __bf16 hh = (__bf16)xs[e];
            hv[e] = hh;
            lv[e] = (__bf16)(xs[e] - (float)hh);
        }
        *(bf16x8*)(ldsbuf + aoff)        = hv;
        *(bf16x8*)(ldsbuf + APAN + aoff) = lv;
    }

    for (int n = 0; n < NIT; ++n) {
        const int ct = n >> 3;
        const int kc = n & 7;
        const int p  = n & 1;

        __syncthreads();   // buffers[p] ready, buffers[p^1] free

        const char* Ab = ldsbuf + p * ABUF;
        const char* Bb = ldsbuf + 2 * ABUF + p * BBUF;

        // ---- issue async B staging for n+1 into buffer p^1 ----
        if (n + 1 < NIT) {
            const char* gsrc = cbP + (panel0 + n + 1) * BBUF;
            char* Bdst = ldsbuf + 2 * ABUF + (p ^ 1) * BBUF;
            #pragma unroll
            for (int c = 0; c < 4; ++c) {
                int off = (wave * 4 + c) * 1024 + lane * 16;
                async_copy16(gsrc + off, Bdst + off);
            }
        }
        // ---- issue z loads for n+1 ----
        float4 za, zb;
        if (n + 1 < NIT) {
            int kc1 = (n + 1) & 7;
            za = z4[(size_t)(row0 + arow) * 64 + kc1 * 8 + aseg * 2 + 0];
            zb = z4[(size_t)(row0 + arow) * 64 + kc1 * 8 + aseg * 2 + 1];
        }

        // ---- compute: fragment reads are (tile*64+lane)*16, sequential ----
        bf16x8 ah[4], bh[2], bl[2], al[4];
        #pragma unroll
        for (int i = 0; i < 4; ++i)
            ah[i] = *(const bf16x8*)(Ab + (i * 64 + lane) * 16);
        #pragma unroll
        for (int j = 0; j < 2; ++j)
            bh[j] = *(const bf16x8*)(Bb + ((wave * 2 + j) * 64 + lane) * 16);
        #pragma unroll
        for (int i = 0; i < 4; ++i)
            #pragma unroll
            for (int j = 0; j < 2; ++j)
                acc[i][j] = __builtin_amdgcn_mfma_f32_16x16x32_bf16(
                                ah[i], bh[j], acc[i][j], 0, 0, 0);
        #pragma unroll
        for (int j = 0; j < 2; ++j)
            bl[j] = *(const bf16x8*)(Bb + BPAN + ((wave * 2 + j) * 64 + lane) * 16);
        #pragma unroll
        for (int i = 0; i < 4; ++i)
            #pragma unroll
            for (int j = 0; j < 2; ++j)
                acc[i][j] = __builtin_amdgcn_mfma_f32_16x16x32_bf16(
                                ah[i], bl[j], acc[i][j], 0, 0, 0);
        #pragma unroll
        for (int i = 0; i < 4; ++i)
            al[i] = *(const bf16x8*)(Ab + APAN + (i * 64 + lane) * 16);
        #pragma unroll
        for (int i = 0; i < 4; ++i)
            #pragma unroll
            for (int j = 0; j < 2; ++j)
                acc[i][j] = __builtin_amdgcn_mfma_f32_16x16x32_bf16(
                                al[i], bh[j], acc[i][j], 0, 0, 0);

        // ---- epilogue at end of code-tile: dist = ||c||^2 - 2 z.c ----
        if (kc == 7) {
            #pragma unroll
            for (int j = 0; j < 2; ++j) {
                int code = qcode + ct * BN + (wave * 2 + j) * 16 + l15;
                float cn = cnorm[code];
                #pragma unroll
                for (int i = 0; i < 4; ++i) {
                    #pragma unroll
                    for (int r = 0; r < 4; ++r) {
                        float d = fmaf(-2.f, acc[i][j][r], cn);
                        int s = i * 4 + r;
                        if (d < mv[s]) { mv[s] = d; mi[s] = code; }
                    }
                    acc[i][j] = (f32x4){0.f, 0.f, 0.f, 0.f};
                }
            }
        }

        // ---- convert + LDS-write A for n+1 into buffer p^1 ----
        if (n + 1 < NIT) {
            float xs[8] = {za.x, za.y, za.z, za.w, zb.x, zb.y, zb.z, zb.w};
            bf16x8 hv, lv;
            #pragma unroll
            for (int e = 0; e < 8; ++e) {
                __bf16 hh = (__bf16)xs[e];
                hv[e] = hh;
                lv[e] = (__bf16)(xs[e] - (float)hh);
            }
            char* Adst = ldsbuf + (p ^ 1) * ABUF;
            *(bf16x8*)(Adst + aoff)        = hv;
            *(bf16x8*)(Adst + APAN + aoff) = lv;
        }
    }

    // ---- reduction: 16-lane butterfly (codes), then cross-wave via LDS ----
    #pragma unroll
    for (int s = 0; s < 16; ++s) {
        #pragma unroll
        for (int m = 1; m <= 8; m <<= 1) {
            float ov = __shfl_xor(mv[s], m, 64);
            int   oi = __shfl_xor(mi[s], m, 64);
            if (ov < mv[s] || (ov == mv[s] && oi < mi[s])) { mv[s] = ov; mi[s] = oi; }
        }
    }
    __syncthreads();
    float* redV = (float*)ldsbuf;               // [4 wave][64 rows]
    int*   redI = (int*)(ldsbuf + 4 * BM * 4);
    if (l15 == 0) {
        int qq = lane >> 4;
        #pragma unroll
        for (int i = 0; i < 4; ++i)
            #pragma unroll
            for (int r = 0; r < 4; ++r) {
                int ml = i * 16 + qq * 4 + r;
                redV[wave * BM + ml] = mv[i * 4 + r];
                redI[wave * BM + ml] = mi[i * 4 + r];
            }
    }
    __syncthreads();
    if (t < BM) {
        float bv = redV[t];
        int   bi = redI[t];
        #pragma unroll
        for (int w = 1; w < 4; ++w) {
            float v  = redV[w * BM + t];
            int   id = redI[w * BM + t];
            if (v < bv || (v == bv && id < bi)) { bv = v; bi = id; }
        }
        partD[(size_t)q * NROWS + row0 + t] = bv;
        partI[(size_t)q * NROWS + row0 + t] = bi;
    }
}

// ---------------------------------------------------------------------------
// K3: merge 4 quarter-partials per row -> final index (ascending q keeps
// numpy first-min tie-breaking).
// ---------------------------------------------------------------------------
__global__ void vq_merge_kernel(const float* __restrict__ partD,
                                const int* __restrict__ partI,
                                float* __restrict__ idx_out) {
    const int row = blockIdx.x * 256 + threadIdx.x;
    float bv = partD[row];
    int   bi = partI[row];
    #pragma unroll
    for (int q = 1; q < NQ; ++q) {
        float v  = partD[(size_t)q * NROWS + row];
        int   id = partI[(size_t)q * NROWS + row];
        if (v < bv || (v == bv && id < bi)) { bv = v; bi = id; }
    }
    idx_out[row] = (float)bi;
}

// ---------------------------------------------------------------------------
// K4: gather codebook rows into quantized output (bit-exact fp32).
// ---------------------------------------------------------------------------
__global__ void vq_gather_kernel(const float* __restrict__ cb,
                                 const float* __restrict__ idx_f,
                                 float* __restrict__ quant) {
    const int t   = threadIdx.x;
    const int row = blockIdx.x * 64 + (t >> 2);
    const int seg = t & 3;
    const int best = (int)idx_f[row];
    const float4* src = (const float4*)cb + (size_t)best * (KDIM / 4);
    float4* dst = (float4*)quant + (size_t)row * (KDIM / 4);
    #pragma unroll
    for (int i = 0; i < 16; ++i)
        dst[seg * 16 + i] = src[seg * 16 + i];
}

// ---------------------------------------------------------------------------
extern "C" void kernel_launch(void* const* d_in, const int* in_sizes, int n_in,
                              void* d_out, int out_size, void* d_ws, size_t ws_size,
                              hipStream_t stream) {
    const float* z  = (const float*)d_in[0];
    const float* cb = (const float*)d_in[1];
    float* quant   = (float*)d_out;
    float* idx_out = (float*)d_out + QOUT_OFFSET;
    float* cnorm   = (float*)d_ws;                 // 32 KB scratch
    char*  cbP     = (char*)d_out;                 // 8 MB panels in quant region
    float* partD   = (float*)((char*)d_out + 8 * 1024 * 1024);   // 512 KB
    int*   partI   = (int*)((char*)d_out + 8 * 1024 * 1024 + NQ * NROWS * 4);
    // panels+partials live inside the 33.5 MB quant region; K4 overwrites last

    vq_panel_kernel<<<NCODES / 64, 256, 0, stream>>>(cb, cbP, cnorm);
    vq_main_kernel<<<NQ * (NROWS / BM), THREADS, 0, stream>>>(z, cbP, cnorm, partD, partI);
    vq_merge_kernel<<<NROWS / 256, 256, 0, stream>>>(partD, partI, idx_out);
    vq_gather_kernel<<<NROWS / 64, 256, 0, stream>>>(cb, idx_out, quant);
}

// Round 8
// 420.902 us; speedup vs baseline: 1.4407x; 1.3487x over previous
//
#include <hip/hip_runtime.h>
#include <cfloat>
#include <stdint.h>

// Problem constants
#define NROWS   32768
#define NCODES  8192
#define KDIM    256
#define QOUT_OFFSET (NROWS * KDIM)

// Main-kernel tiling
#define BM      64              // rows per block
#define BN      256             // codes per block-tile (4 waves x 64)
#define NQ      4               // codebook quarters
#define CODES_Q (NCODES / NQ)   // 2048
#define NKC     (KDIM / 32)     // 8
#define NIT     (CODES_Q / BN * NKC)   // 8 ct * 8 kc = 64
#define THREADS 256             // 4 waves

// Fragment-order panel geometry (per 128-code panel)
#define BPAN 8192               // 128 codes * 32 k * 2 B, one split
#define BBUF (2 * BPAN)         // hi+lo 16384
#define ALDS_SPLIT 32768        // 64 rows * 256 k * 2 B per split
// LDS: 2 * 32768 = 65536 B -> 2 blocks/CU

typedef __bf16 bf16x4 __attribute__((ext_vector_type(4)));
typedef __bf16 bf16x8 __attribute__((ext_vector_type(8)));
typedef float  f32x4  __attribute__((ext_vector_type(4)));

// ---------------------------------------------------------------------------
// K1: codebook -> hi/lo bf16 panels in MFMA-fragment order, + cnorm.
// Panel p = (code>>7)*8 + kc. Within panel: tile j=(code&127)>>4,
// frag-lane = ((kl>>3)<<4) | (code&15), slot byte = (j*64+lane)*16 + (kl&7)*2.
// ---------------------------------------------------------------------------
__global__ void vq_panel_kernel(const float* __restrict__ cb,
                                char* __restrict__ cbP,
                                float* __restrict__ cnorm) {
    const int t    = threadIdx.x;
    const int row  = t >> 2;
    const int seg  = t & 3;
    const int code = blockIdx.x * 64 + row;
    const int cl   = code & 127;
    const int pt   = code >> 7;
    const float4* cb4 = (const float4*)cb;

    float ssq = 0.f;
    #pragma unroll
    for (int i = 0; i < 16; ++i) {
        int f = seg * 16 + i;            // float4 index in row, 0..63
        float4 v = cb4[(size_t)code * 64 + f];
        int k   = f * 4;
        int kc  = k >> 5;
        int kl  = k & 31;
        int oct = kl >> 3;
        int rem = kl & 7;                // 0 or 4
        bf16x4 h, l;
        float xs[4] = {v.x, v.y, v.z, v.w};
        #pragma unroll
        for (int e = 0; e < 4; ++e) {
            __bf16 hh = (__bf16)xs[e];
            h[e] = hh;
            l[e] = (__bf16)(xs[e] - (float)hh);
            ssq  = fmaf(xs[e], xs[e], ssq);
        }
        int lanefrag = (oct << 4) | (cl & 15);
        char* base = cbP + ((size_t)(pt * NKC + kc)) * BBUF
                         + ((cl >> 4) * 64 + lanefrag) * 16 + rem * 2;
        *(bf16x4*)base          = h;
        *(bf16x4*)(base + BPAN) = l;
    }
    ssq += __shfl_xor(ssq, 1, 64);
    ssq += __shfl_xor(ssq, 2, 64);
    if (seg == 0) cnorm[code] = ssq;
}

// ---------------------------------------------------------------------------
// K2: split-bf16 MFMA distances + per-quarter argmin partials.
// Barrier-free K-loop: A (z hi/lo, frag-order, full K=256) staged in LDS once;
// B fragments loaded global->VGPR (coalesced, L2-resident panels), 1-deep
// register prefetch. Wave tile 64 rows x 64 codes, 48 MFMAs/iter, no
// __syncthreads in the hot loop.
// ---------------------------------------------------------------------------
__global__ __launch_bounds__(THREADS, 2) void vq_main_kernel(
        const float* __restrict__ z, const char* __restrict__ cbP,
        const float* __restrict__ cnorm,
        float* __restrict__ partD, int* __restrict__ partI) {

    __shared__ __align__(16) char Alds[2 * ALDS_SPLIT];   // 65536 B

    const int t     = threadIdx.x;
    const int wave  = t >> 6;
    const int lane  = t & 63;
    const int l15   = lane & 15;
    const int q     = blockIdx.x >> 9;
    const int row0  = (blockIdx.x & 511) * BM;
    const int qcode = q * CODES_Q;
    const int qp16  = q * 16;              // global 128-code panel-group base

    const float4* z4 = (const float4*)z;

    f32x4 acc[4][4];
    float mv[16];
    int   mi[16];
    #pragma unroll
    for (int i = 0; i < 4; ++i)
        #pragma unroll
        for (int j = 0; j < 4; ++j)
            acc[i][j] = (f32x4){0.f, 0.f, 0.f, 0.f};
    #pragma unroll
    for (int s = 0; s < 16; ++s) { mv[s] = FLT_MAX; mi[s] = 0; }

    // ---- prologue: stage A (all 8 kc, hi+lo, fragment order) ----
    {
        const int arow = t >> 2;
        const int aseg = t & 3;
        #pragma unroll
        for (int p = 0; p < 8; ++p) {
            float4 f0 = z4[(size_t)(row0 + arow) * 64 + aseg * 16 + 2 * p];
            float4 f1 = z4[(size_t)(row0 + arow) * 64 + aseg * 16 + 2 * p + 1];
            float xs[8] = {f0.x, f0.y, f0.z, f0.w, f1.x, f1.y, f1.z, f1.w};
            bf16x8 hv, lv;
            #pragma unroll
            for (int e = 0; e < 8; ++e) {
                __bf16 hh = (__bf16)xs[e];
                hv[e] = hh;
                lv[e] = (__bf16)(xs[e] - (float)hh);
            }
            int kc  = aseg * 2 + (p >> 2);
            int oct = p & 3;
            int slot = ((kc * 4 + (arow >> 4)) * 64 + (oct << 4) + (arow & 15)) * 16;
            *(bf16x8*)(Alds + slot)              = hv;
            *(bf16x8*)(Alds + ALDS_SPLIT + slot) = lv;
        }
    }

    // ---- prologue: load B fragments for iter 0 ----
    bf16x8 B0h[4], B0l[4], B1h[4], B1l[4];
    #pragma unroll
    for (int j = 0; j < 4; ++j) {
        int g16 = wave * 4 + j;            // ct=0
        const char* pb = cbP + ((size_t)(qp16 + (g16 >> 3)) * 8 + 0) * BBUF
                             + ((g16 & 7) * 64 + lane) * 16;
        B0h[j] = *(const bf16x8*)pb;
        B0l[j] = *(const bf16x8*)(pb + BPAN);
    }

    __syncthreads();   // A ready; the ONLY barrier before the reduction

#define VQ_BODY(N, CURH, CURL, NXTH, NXTL)                                    \
    {                                                                         \
        const int ct = (N) >> 3, kc = (N) & 7;                                \
        const int np = (N) + 1;                                               \
        if (np < NIT) {                                                       \
            const int ct1 = np >> 3, kc1 = np & 7;                            \
            _Pragma("unroll")                                                 \
            for (int j = 0; j < 4; ++j) {                                     \
                int g16 = ct1 * 16 + wave * 4 + j;                            \
                const char* pb = cbP                                          \
                    + ((size_t)(qp16 + (g16 >> 3)) * 8 + kc1) * BBUF          \
                    + ((g16 & 7) * 64 + lane) * 16;                           \
                NXTH[j] = *(const bf16x8*)pb;                                 \
                NXTL[j] = *(const bf16x8*)(pb + BPAN);                        \
            }                                                                 \
        }                                                                     \
        bf16x8 ah[4], al[4];                                                  \
        _Pragma("unroll")                                                     \
        for (int i = 0; i < 4; ++i) {                                         \
            int sl = ((kc * 4 + i) * 64 + lane) * 16;                         \
            ah[i] = *(const bf16x8*)(Alds + sl);                              \
            al[i] = *(const bf16x8*)(Alds + ALDS_SPLIT + sl);                 \
        }                                                                     \
        _Pragma("unroll")                                                     \
        for (int i = 0; i < 4; ++i)                                           \
            _Pragma("unroll")                                                 \
            for (int j = 0; j < 4; ++j)                                       \
                acc[i][j] = __builtin_amdgcn_mfma_f32_16x16x32_bf16(          \
                                ah[i], CURH[j], acc[i][j], 0, 0, 0);          \
        _Pragma("unroll")                                                     \
        for (int i = 0; i < 4; ++i)                                           \
            _Pragma("unroll")                                                 \
            for (int j = 0; j < 4; ++j)                                       \
                acc[i][j] = __builtin_amdgcn_mfma_f32_16x16x32_bf16(          \
                                ah[i], CURL[j], acc[i][j], 0, 0, 0);          \
        _Pragma("unroll")                                                     \
        for (int i = 0; i < 4; ++i)                                           \
            _Pragma("unroll")                                                 \
            for (int j = 0; j < 4; ++j)                                       \
                acc[i][j] = __builtin_amdgcn_mfma_f32_16x16x32_bf16(          \
                                al[i], CURH[j], acc[i][j], 0, 0, 0);          \
        if (kc == 7) {                                                        \
            _Pragma("unroll")                                                 \
            for (int j = 0; j < 4; ++j) {                                     \
                int code = qcode + (ct * 16 + wave * 4 + j) * 16 + l15;       \
                float cn = cnorm[code];                                       \
                _Pragma("unroll")                                             \
                for (int i = 0; i < 4; ++i) {                                 \
                    _Pragma("unroll")                                         \
                    for (int r = 0; r < 4; ++r) {                             \
                        float d = fmaf(-2.f, acc[i][j][r], cn);               \
                        int s = i * 4 + r;                                    \
                        if (d < mv[s]) { mv[s] = d; mi[s] = code; }           \
                    }                                                         \
                    acc[i][j] = (f32x4){0.f, 0.f, 0.f, 0.f};                  \
                }                                                             \
            }                                                                 \
        }                                                                     \
    }

    for (int n = 0; n < NIT; n += 2) {
        VQ_BODY(n,     B0h, B0l, B1h, B1l)
        VQ_BODY(n + 1, B1h, B1l, B0h, B0l)
    }
#undef VQ_BODY

    // ---- reduction: 16-lane butterfly (codes), then cross-wave via LDS ----
    #pragma unroll
    for (int s = 0; s < 16; ++s) {
        #pragma unroll
        for (int m = 1; m <= 8; m <<= 1) {
            float ov = __shfl_xor(mv[s], m, 64);
            int   oi = __shfl_xor(mi[s], m, 64);
            if (ov < mv[s] || (ov == mv[s] && oi < mi[s])) { mv[s] = ov; mi[s] = oi; }
        }
    }
    __syncthreads();
    float* redV = (float*)Alds;                 // [4 wave][64 rows]
    int*   redI = (int*)(Alds + 4 * BM * 4);
    if (l15 == 0) {
        int qq = lane >> 4;
        #pragma unroll
        for (int i = 0; i < 4; ++i)
            #pragma unroll
            for (int r = 0; r < 4; ++r) {
                int ml = i * 16 + qq * 4 + r;
                redV[wave * BM + ml] = mv[i * 4 + r];
                redI[wave * BM + ml] = mi[i * 4 + r];
            }
    }
    __syncthreads();
    if (t < BM) {
        float bv = redV[t];
        int   bi = redI[t];
        #pragma unroll
        for (int w = 1; w < 4; ++w) {
            float v  = redV[w * BM + t];
            int   id = redI[w * BM + t];
            if (v < bv || (v == bv && id < bi)) { bv = v; bi = id; }
        }
        partD[(size_t)q * NROWS + row0 + t] = bv;
        partI[(size_t)q * NROWS + row0 + t] = bi;
    }
}

// ---------------------------------------------------------------------------
// K3: merge 4 quarter-partials per row -> final index (ascending q keeps
// numpy first-min tie-breaking).
// ---------------------------------------------------------------------------
__global__ void vq_merge_kernel(const float* __restrict__ partD,
                                const int* __restrict__ partI,
                                float* __restrict__ idx_out) {
    const int row = blockIdx.x * 256 + threadIdx.x;
    float bv = partD[row];
    int   bi = partI[row];
    #pragma unroll
    for (int q = 1; q < NQ; ++q) {
        float v  = partD[(size_t)q * NROWS + row];
        int   id = partI[(size_t)q * NROWS + row];
        if (v < bv || (v == bv && id < bi)) { bv = v; bi = id; }
    }
    idx_out[row] = (float)bi;
}

// ---------------------------------------------------------------------------
// K4: gather codebook rows into quantized output (bit-exact fp32).
// ---------------------------------------------------------------------------
__global__ void vq_gather_kernel(const float* __restrict__ cb,
                                 const float* __restrict__ idx_f,
                                 float* __restrict__ quant) {
    const int t   = threadIdx.x;
    const int row = blockIdx.x * 64 + (t >> 2);
    const int seg = t & 3;
    const int best = (int)idx_f[row];
    const float4* src = (const float4*)cb + (size_t)best * (KDIM / 4);
    float4* dst = (float4*)quant + (size_t)row * (KDIM / 4);
    #pragma unroll
    for (int i = 0; i < 16; ++i)
        dst[seg * 16 + i] = src[seg * 16 + i];
}

// ---------------------------------------------------------------------------
extern "C" void kernel_launch(void* const* d_in, const int* in_sizes, int n_in,
                              void* d_out, int out_size, void* d_ws, size_t ws_size,
                              hipStream_t stream) {
    const float* z  = (const float*)d_in[0];
    const float* cb = (const float*)d_in[1];
    float* quant   = (float*)d_out;
    float* idx_out = (float*)d_out + QOUT_OFFSET;
    float* cnorm   = (float*)d_ws;                 // 32 KB scratch
    char*  cbP     = (char*)d_out;                 // 8 MB panels in quant region
    float* partD   = (float*)((char*)d_out + 8 * 1024 * 1024);   // 512 KB
    int*   partI   = (int*)((char*)d_out + 8 * 1024 * 1024 + NQ * NROWS * 4);
    // panels+partials live inside the 32 MB quant region; K4 overwrites last

    vq_panel_kernel<<<NCODES / 64, 256, 0, stream>>>(cb, cbP, cnorm);
    vq_main_kernel<<<NQ * (NROWS / BM), THREADS, 0, stream>>>(z, cbP, cnorm, partD, partI);
    vq_merge_kernel<<<NROWS / 256, 256, 0, stream>>>(partD, partI, idx_out);
    vq_gather_kernel<<<NROWS / 64, 256, 0, stream>>>(cb, idx_out, quant);
}